// Round 2
// 96.535 us; speedup vs baseline: 1.0509x; 1.0509x over previous
//
#include <hip/hip_runtime.h>

#define N_NODES 8192
#define DOUT    512
#define LOG2E   1.4426950408889634f
#define SQRT3   1.7320508075688772f

// raw v_exp_f32 (D = 2^S0) — single trans-pipe instruction
__device__ __forceinline__ float exp2_raw(float x) {
    float r;
    asm("v_exp_f32 %0, %1" : "=v"(r) : "v"(x));
    return r;
}

// ws float layout: aux[32] at 0   (G*log2e [0..8], g0*log2e [9..11], Cmax partials [12..19])
//                  T[512*8] at 32 (R3[3], h, M3[3], pad) — 128 B offset, 16B aligned

// K2: blocks 0..511   -> epilogue table row T[r]        (128 thr = 2 waves/row)
//     blocks 512..523 -> aux[o]: G = Wq3^T Wk3, g0 = Wq3^T kc (both *log2e)
//     blocks 524..531 -> aux[12+b]: partial max |node component| over 1024 nodes
__global__ __launch_bounds__(128) void k2_tables_aux(
    const float* __restrict__ nodes, const float* __restrict__ centre,
    const float* __restrict__ Wq, const float* __restrict__ bq,
    const float* __restrict__ Wk, const float* __restrict__ bk,
    const float* __restrict__ Wv, const float* __restrict__ bv,
    float* __restrict__ T, float* __restrict__ aux)
{
    __shared__ float red[16];
    const int r = blockIdx.x, tid = threadIdx.x, lane = tid & 63, wv = tid >> 6;
    const float c0 = centre[0], c1 = centre[1], c2 = centre[2];

    if (r < 512) {
        // T[r] = { R3 = Wk3[r] + Wv_k[r]@Wk3,
        //          h  = kc[r] + Wv_k[r].kc + Wv_q[r].u + bv[r],
        //          M3 = Wv_q[r]@Wq3 }
        const float* wvq = Wv + (size_t)r * 1024;   // Wv[r, :512]
        const float* wvk = wvq + 512;               // Wv[r, 512:]

        float m0=0.f,m1=0.f,m2=0.f,uc=0.f,r0=0.f,r1=0.f,r2=0.f,rc=0.f;
        #pragma unroll
        for (int it = 0; it < 4; ++it) {
            int s = it*128 + tid;
            float a = wvq[s];
            float b = wvk[s];
            const float2* wk2 = (const float2*)(Wk + s*6);  // rows are 24B -> 8B aligned
            const float2* wq2 = (const float2*)(Wq + s*6);
            float2 k01 = wk2[0], k23 = wk2[1], k45 = wk2[2];
            float2 q01 = wq2[0], q23 = wq2[1], q45 = wq2[2];
            float kcs = fmaf(k23.y, c0, fmaf(k45.x, c1, fmaf(k45.y, c2, bk[s])));
            float us  = fmaf(q23.y, c0, fmaf(q45.x, c1, fmaf(q45.y, c2, bq[s])));
            m0 = fmaf(a, q01.x, m0);
            m1 = fmaf(a, q01.y, m1);
            m2 = fmaf(a, q23.x, m2);
            uc = fmaf(a, us, uc);
            r0 = fmaf(b, k01.x, r0);
            r1 = fmaf(b, k01.y, r1);
            r2 = fmaf(b, k23.x, r2);
            rc = fmaf(b, kcs, rc);
        }
        #pragma unroll
        for (int off = 32; off; off >>= 1) {
            m0 += __shfl_xor(m0, off); m1 += __shfl_xor(m1, off);
            m2 += __shfl_xor(m2, off); uc += __shfl_xor(uc, off);
            r0 += __shfl_xor(r0, off); r1 += __shfl_xor(r1, off);
            r2 += __shfl_xor(r2, off); rc += __shfl_xor(rc, off);
        }
        if (lane == 0) {
            float* q = red + wv*8;
            q[0]=m0; q[1]=m1; q[2]=m2; q[3]=uc; q[4]=r0; q[5]=r1; q[6]=r2; q[7]=rc;
        }
        __syncthreads();
        if (tid == 0) {
            float kcr = fmaf(Wk[r*6+3], c0, fmaf(Wk[r*6+4], c1,
                        fmaf(Wk[r*6+5], c2, bk[r])));
            T[r*8+0] = Wk[r*6+0] + red[4] + red[12];
            T[r*8+1] = Wk[r*6+1] + red[5] + red[13];
            T[r*8+2] = Wk[r*6+2] + red[6] + red[14];
            T[r*8+3] = kcr + red[7] + red[15] + red[3] + red[11] + bv[r];
            T[r*8+4] = red[0] + red[8];
            T[r*8+5] = red[1] + red[9];
            T[r*8+6] = red[2] + red[10];
            T[r*8+7] = 0.f;
        }
    } else if (r < 524) {
        const int o = r - 512;   // 0..11
        float acc = 0.f;
        if (o < 9) {
            int a = o / 3, b = o - a*3;
            #pragma unroll
            for (int it = 0; it < 4; ++it) {
                int s = it*128 + tid;
                acc = fmaf(Wq[s*6+a], Wk[s*6+b], acc);
            }
        } else {
            int a = o - 9;
            #pragma unroll
            for (int it = 0; it < 4; ++it) {
                int s = it*128 + tid;
                float kc = fmaf(Wk[s*6+3], c0, fmaf(Wk[s*6+4], c1,
                           fmaf(Wk[s*6+5], c2, bk[s])));
                acc = fmaf(Wq[s*6+a], kc, acc);
            }
        }
        #pragma unroll
        for (int off = 32; off; off >>= 1) acc += __shfl_xor(acc, off);
        if (lane == 0) red[wv] = acc;
        __syncthreads();
        if (tid == 0) aux[o] = (red[0] + red[1]) * LOG2E;
    } else {
        // partial max |component| over 1024 nodes (768 float4), one writer per slot
        const int b = r - 524;   // 0..7
        const float4* src = (const float4*)nodes + (size_t)b * 768;
        float m = 0.f;
        #pragma unroll
        for (int it = 0; it < 6; ++it) {
            float4 v = src[it*128 + tid];
            m = fmaxf(m, fmaxf(fmaxf(fabsf(v.x), fabsf(v.y)),
                               fmaxf(fabsf(v.z), fabsf(v.w))));
        }
        #pragma unroll
        for (int off = 32; off; off >>= 1) m = fmaxf(m, __shfl_xor(m, off));
        if (lane == 0) red[wv] = m;
        __syncthreads();
        if (tid == 0) aux[12 + b] = fmaxf(red[0], red[1]);
    }
}

// ---- K3 helpers: SoA staging (register transpose) + b128 inner loop ----

// each thread loads 3 consecutive float4 (= 4 nodes, 12 floats) per k
__device__ __forceinline__ void stage_load(const float4* __restrict__ src, int tid,
                                           float4 v[4][3]) {
    #pragma unroll
    for (int k = 0; k < 4; ++k) {
        int t = k*256 + tid;                 // triple index 0..1023
        v[k][0] = src[t*3+0];
        v[k][1] = src[t*3+1];
        v[k][2] = src[t*3+2];
    }
}

// AoS->SoA in registers, then 3 contiguous ds_write_b128 (conflict-free)
__device__ __forceinline__ void stage_write(float* __restrict__ lds, int tid,
                                            float4 v[4][3]) {
    #pragma unroll
    for (int k = 0; k < 4; ++k) {
        int t = k*256 + tid;
        float4 a = v[k][0], b = v[k][1], c = v[k][2];
        // a=(x0,y0,z0,x1) b=(y1,z1,x2,y2) c=(z2,x3,y3,z3)
        *(float4*)&lds[        t*4] = make_float4(a.x, a.w, b.z, c.y);  // X plane
        *(float4*)&lds[4096 +  t*4] = make_float4(a.y, b.x, b.w, c.z);  // Y plane
        *(float4*)&lds[8192 +  t*4] = make_float4(a.z, b.y, c.x, c.w);  // Z plane
    }
}

// inner loop over one 4096-node tile: 3 ds_read_b128 per 4 j's (vs 12 ds_read_b32)
__device__ __forceinline__ void attn_tile(const float* __restrict__ lds, int lane,
    const float vx[4], const float vy[4], const float vz[4], const float bb[4],
    float S[4], float ax[4], float ay[4], float az[4])
{
    #pragma unroll 2
    for (int it = 0; it < 16; ++it) {
        int jj = it*256 + lane*4;
        float4 X = *(const float4*)&lds[jj];
        float4 Y = *(const float4*)&lds[4096 + jj];
        float4 Z = *(const float4*)&lds[8192 + jj];
        #pragma unroll
        for (int q = 0; q < 4; ++q) {
            float a0 = fmaf(vx[q],X.x, fmaf(vy[q],Y.x, fmaf(vz[q],Z.x, bb[q])));
            float a1 = fmaf(vx[q],X.y, fmaf(vy[q],Y.y, fmaf(vz[q],Z.y, bb[q])));
            float a2 = fmaf(vx[q],X.z, fmaf(vy[q],Y.z, fmaf(vz[q],Z.z, bb[q])));
            float a3 = fmaf(vx[q],X.w, fmaf(vy[q],Y.w, fmaf(vz[q],Z.w, bb[q])));
            float e0 = exp2_raw(a0);
            float e1 = exp2_raw(a1);
            float e2 = exp2_raw(a2);
            float e3 = exp2_raw(a3);
            S[q] += e0; ax[q]=fmaf(e0,X.x,ax[q]); ay[q]=fmaf(e0,Y.x,ay[q]); az[q]=fmaf(e0,Z.x,az[q]);
            S[q] += e1; ax[q]=fmaf(e1,X.y,ax[q]); ay[q]=fmaf(e1,Y.y,ay[q]); az[q]=fmaf(e1,Z.y,az[q]);
            S[q] += e2; ax[q]=fmaf(e2,X.z,ax[q]); ay[q]=fmaf(e2,Y.z,ay[q]); az[q]=fmaf(e2,Z.z,az[q]);
            S[q] += e3; ax[q]=fmaf(e3,X.w,ax[q]); ay[q]=fmaf(e3,Y.w,ay[q]); az[q]=fmaf(e3,Z.w,az[q]);
        }
    }
}

// K3: per-row softmax-weighted mean node position + fused epilogue.
// 512 blocks x 256 threads (4 waves, 4 rows/wave); nodes in SoA LDS planes
// (48 KB static); tile-1 global loads prefetched into registers under tile-0 compute.
__global__ __launch_bounds__(256, 2) void k3_attn(
    const float* __restrict__ nodes,
    const float* __restrict__ aux, const float* __restrict__ T,
    float* __restrict__ out)
{
    __shared__ float lds[12288];   // SoA: X[0..4095], Y[4096..8191], Z[8192..12287]
    const int tid = threadIdx.x, lane = tid & 63, wv = tid >> 6;
    const int ibase = (blockIdx.x * 4 + wv) * 4;

    const float G00=aux[0],G01=aux[1],G02=aux[2];
    const float G10=aux[3],G11=aux[4],G12=aux[5];
    const float G20=aux[6],G21=aux[7],G22=aux[8];
    const float g0=aux[9],g1=aux[10],g2=aux[11];
    float C = aux[12];
    #pragma unroll
    for (int b = 1; b < 8; ++b) C = fmaxf(C, aux[12+b]);
    const float Nbound = SQRT3 * C;   // |n_j| <= sqrt(3) * max|component|

    float nx_[4], ny_[4], nz_[4], vx[4], vy[4], vz[4], bb[4];
    float S[4], ax[4], ay[4], az[4];
    #pragma unroll
    for (int q = 0; q < 4; ++q) {
        int i = ibase + q;
        float x = nodes[3*i], y = nodes[3*i+1], z = nodes[3*i+2];
        nx_[q]=x; ny_[q]=y; nz_[q]=z;
        float a = fmaf(G00,x, fmaf(G01,y, fmaf(G02,z, g0)));
        float b = fmaf(G10,x, fmaf(G11,y, fmaf(G12,z, g1)));
        float c = fmaf(G20,x, fmaf(G21,y, fmaf(G22,z, g2)));
        vx[q]=a; vy[q]=b; vz[q]=c;
        // Cauchy-Schwarz bound (log2 scale): arg <= ~0 always; shift cancels in softmax
        bb[q] = -sqrtf(fmaf(a,a, fmaf(b,b, c*c))) * Nbound;
        S[q]=0.f; ax[q]=0.f; ay[q]=0.f; az[q]=0.f;
    }

    // tile 0 stage, then ISSUE tile-1 loads before compute (waitcnt lands at write)
    float4 s0[4][3], s1[4][3];
    stage_load((const float4*)nodes, tid, s0);
    stage_write(lds, tid, s0);
    stage_load((const float4*)(nodes + 12288), tid, s1);
    __syncthreads();
    attn_tile(lds, lane, vx, vy, vz, bb, S, ax, ay, az);
    __syncthreads();
    stage_write(lds, tid, s1);
    __syncthreads();
    attn_tile(lds, lane, vx, vy, vz, bb, S, ax, ay, az);

    #pragma unroll
    for (int q = 0; q < 4; ++q) {
        #pragma unroll
        for (int off = 32; off; off >>= 1) {
            S[q]  += __shfl_xor(S[q],  off);
            ax[q] += __shfl_xor(ax[q], off);
            ay[q] += __shfl_xor(ay[q], off);
            az[q] += __shfl_xor(az[q], off);
        }
        float inv = 1.f / fmaxf(S[q], 1e-35f);
        ax[q] *= inv; ay[q] *= inv; az[q] *= inv;   // ā_i
    }

    // epilogue: out[i][d] = R3[d].n_i + M3[d].ā_i + h[d]; float2 stores (coalesced)
    const float4* T4 = (const float4*)T;
    #pragma unroll
    for (int t = 0; t < 4; ++t) {
        int d0 = t*128 + lane*2;
        float4 A0 = T4[2*d0+0], B0 = T4[2*d0+1];
        float4 A1 = T4[2*d0+2], B1 = T4[2*d0+3];
        #pragma unroll
        for (int q = 0; q < 4; ++q) {
            float v0 = fmaf(A0.x,nx_[q], fmaf(A0.y,ny_[q], fmaf(A0.z,nz_[q],
                       fmaf(B0.x,ax[q], fmaf(B0.y,ay[q], fmaf(B0.z,az[q], A0.w))))));
            float v1 = fmaf(A1.x,nx_[q], fmaf(A1.y,ny_[q], fmaf(A1.z,nz_[q],
                       fmaf(B1.x,ax[q], fmaf(B1.y,ay[q], fmaf(B1.z,az[q], A1.w))))));
            *(float2*)(out + (size_t)(ibase+q)*DOUT + d0) = make_float2(v0, v1);
        }
    }
}

extern "C" void kernel_launch(void* const* d_in, const int* in_sizes, int n_in,
                              void* d_out, int out_size, void* d_ws, size_t ws_size,
                              hipStream_t stream) {
    const float* nodes  = (const float*)d_in[0];
    const float* centre = (const float*)d_in[1];
    const float* Wq     = (const float*)d_in[2];
    const float* bq     = (const float*)d_in[3];
    const float* Wk     = (const float*)d_in[4];
    const float* bk     = (const float*)d_in[5];
    const float* Wv     = (const float*)d_in[6];
    const float* bv     = (const float*)d_in[7];

    float* ws  = (float*)(((uintptr_t)d_ws + 255) & ~(uintptr_t)255);
    float* aux = ws;        // 32 floats
    float* T   = ws + 32;   // 4096 floats, 128 B offset
    float* out = (float*)d_out;

    hipLaunchKernelGGL(k2_tables_aux, dim3(532), dim3(128), 0, stream,
                       nodes, centre, Wq, bq, Wk, bk, Wv, bv, T, aux);
    hipLaunchKernelGGL(k3_attn,       dim3(512), dim3(256), 0, stream,
                       nodes, aux, T, out);
}